// Round 1
// baseline (292.381 us; speedup 1.0000x reference)
//
#include <hip/hip_runtime.h>
#include <hip/hip_bf16.h>
#include <math.h>

// ---------- types / helpers ----------
typedef short short8 __attribute__((ext_vector_type(8)));
typedef float floatx4 __attribute__((ext_vector_type(4)));

typedef __attribute__((address_space(1))) unsigned int as1_u32;
typedef __attribute__((address_space(3))) unsigned int as3_u32;

__device__ __forceinline__ void load_lds16(const void* g, void* l) {
  // async 16B/lane global->LDS; HW dest = wave-uniform base + lane*16
  __builtin_amdgcn_global_load_lds((const as1_u32*)g, (as3_u32*)l, 16, 0, 0);
}

__device__ __forceinline__ unsigned short f2bf(float f) {
  __bf16 h = (__bf16)f;
  return __builtin_bit_cast(unsigned short, h);
}

// ---------- constants ----------
#define TB 2
#define TT 2048
#define TC 2048
#define QKN 2560    // qk row stride: 2048 Q + 512 K
#define KOFF 2048
#define SCALE_Q 0.18033688f  // (1/8) * log2(e), folded into Q at projection

// ---------- 0: cast fp32 -> bf16 (x, packed Wqkv, Wo) + rope table ----------
__global__ __launch_bounds__(256) void cast_all(
    const float* __restrict__ x, const float* __restrict__ wq,
    const float* __restrict__ wk, const float* __restrict__ wv,
    const float* __restrict__ wo,
    unsigned short* __restrict__ xb, unsigned short* __restrict__ wqkv,
    unsigned short* __restrict__ wob, float2* __restrict__ ropeTab) {
  // rope table: 2048 t x 32 d (cos,sin) = 512 KB, built by first 256 blocks
  if (blockIdx.x < 256) {
    const int idx = blockIdx.x * 256 + threadIdx.x;  // t*32+d
    const int t = idx >> 5, d = idx & 31;
    const float inv = exp2f((float)d * -0.4152410119f);  // 10000^(-d/32)
    float sn, cs;
    sincosf((float)t * inv, &sn, &cs);
    ropeTab[idx] = make_float2(cs, sn);
  }
  long i4 = (long)blockIdx.x * 256 + threadIdx.x;  // float4 index
  const float* src;
  unsigned short* dst;
  if (i4 < 2097152)      { src = x;  dst = xb; }
  else if (i4 < 3145728) { src = wq; dst = wqkv;           i4 -= 2097152; }
  else if (i4 < 3407872) { src = wk; dst = wqkv + 4194304; i4 -= 3145728; }
  else if (i4 < 3670016) { src = wv; dst = wqkv + 5242880; i4 -= 3407872; }
  else                   { src = wo; dst = wob;            i4 -= 3670016; }
  float4 v = ((const float4*)src)[i4];
  ushort4 o;
  o.x = f2bf(v.x); o.y = f2bf(v.y); o.z = f2bf(v.z); o.w = f2bf(v.w);
  ((ushort4*)dst)[i4] = o;
}

// ---------- 1: QKV GEMM with fused RoPE + Q-scale + V-transpose epilogue ----------
// C[M=4096, N=3072] = xb * wqkv^T.  Q cols [0,2048): rope+scale -> qk;
// K cols [2048,2560): rope -> qk; V cols [2560,3072): transposed -> vT[512][4096].
// Block swizzle: XCD (lin&7) owns a 3-wide N-stripe -> B stays L2-resident.
__global__ __launch_bounds__(256) void gemm_qkv(const unsigned short* __restrict__ A,
                                                const unsigned short* __restrict__ Bw,
                                                unsigned short* __restrict__ qk,
                                                unsigned short* __restrict__ vT,
                                                const float2* __restrict__ ropeTab) {
  __shared__ unsigned short As[128 * 64];
  __shared__ unsigned short Bs[128 * 64];
  const int K = 2048;
  const int tid = threadIdx.x;
  const int lane = tid & 63, w = tid >> 6;
  const int quad = lane >> 4, l15 = lane & 15;
  const int wm = w >> 1, wn = w & 1;
  // XCD-aware swizzle: grid 24x32, lin&7 = XCD, each XCD owns cols [3k, 3k+3)
  const int lin = blockIdx.y * 24 + blockIdx.x;
  const int sub = lin >> 3;
  const int m0 = (sub / 3) * 128;
  const int n0 = ((lin & 7) * 3 + sub % 3) * 128;

  floatx4 acc[4][4];
#pragma unroll
  for (int i = 0; i < 4; ++i)
#pragma unroll
    for (int j = 0; j < 4; ++j) acc[i][j] = (floatx4){0.f, 0.f, 0.f, 0.f};

  const int ar = tid >> 3;
  const int ac = (((tid & 7) ^ (ar & 7)) * 8);  // swizzled col-group
  const unsigned short* Abase = A + (size_t)(m0 + ar) * K + ac;
  const unsigned short* Bbase = Bw + (size_t)(n0 + ar) * K + ac;

  for (int k0 = 0; k0 < K; k0 += 64) {
    __syncthreads();
#pragma unroll
    for (int p = 0; p < 4; ++p) {
      load_lds16(Abase + (size_t)(p * 32) * K + k0, (char*)As + p * 4096 + tid * 16);
      load_lds16(Bbase + (size_t)(p * 32) * K + k0, (char*)Bs + p * 4096 + tid * 16);
    }
    __syncthreads();
#pragma unroll
    for (int ks = 0; ks < 2; ++ks) {
      short8 af[4], bfr[4];
      const int key = (((ks << 2) + quad) ^ (l15 & 7)) << 4;
#pragma unroll
      for (int i = 0; i < 4; ++i)
        af[i] = *(const short8*)((const char*)As + (wm * 64 + i * 16 + l15) * 128 + key);
#pragma unroll
      for (int j = 0; j < 4; ++j)
        bfr[j] = *(const short8*)((const char*)Bs + (wn * 64 + j * 16 + l15) * 128 + key);
#pragma unroll
      for (int i = 0; i < 4; ++i)
#pragma unroll
        for (int j = 0; j < 4; ++j)
          acc[i][j] = __builtin_amdgcn_mfma_f32_16x16x32_bf16(af[i], bfr[j], acc[i][j], 0, 0, 0);
    }
  }

  const int colb = n0 + wn * 64;  // wave-uniform region selector (64-aligned)
  if (colb < QKN) {
    // ---- Q or K: RoPE via table on fp32 acc, optional scale, store to qk ----
    const float qscale = (colb < KOFF) ? SCALE_Q : 1.0f;
#pragma unroll
    for (int i = 0; i < 4; ++i) {
      const int rowb = m0 + wm * 64 + i * 16 + quad * 4;
      const int tb = rowb & (TT - 1);
#pragma unroll
      for (int j = 0; j < 2; ++j) {
        const int col = colb + j * 16 + l15;
        const int d = j * 16 + l15;  // 0..31
#pragma unroll
        for (int r = 0; r < 4; ++r) {
          const float2 cssn = ropeTab[(tb + r) * 32 + d];
          const float a = acc[i][j][r], b2 = acc[i][j + 2][r];
          const float qa = (a * cssn.x - b2 * cssn.y) * qscale;
          const float qb = (b2 * cssn.x + a * cssn.y) * qscale;
          unsigned short* p = qk + (size_t)(rowb + r) * QKN + col;
          p[0] = f2bf(qa);
          p[32] = f2bf(qb);
        }
      }
    }
  } else {
    // ---- V: transposed packed store  vT[col-2560][rowb..rowb+3] ----
#pragma unroll
    for (int i = 0; i < 4; ++i) {
      const int rowb = m0 + wm * 64 + i * 16 + quad * 4;
#pragma unroll
      for (int j = 0; j < 4; ++j) {
        const int col = colb + j * 16 + l15;
        ushort4 pk;
        pk.x = f2bf(acc[i][j][0]); pk.y = f2bf(acc[i][j][1]);
        pk.z = f2bf(acc[i][j][2]); pk.w = f2bf(acc[i][j][3]);
        *(ushort4*)(vT + (size_t)(col - 2560) * 4096 + rowb) = pk;
      }
    }
  }
}

// ---------- 1b: output projection NT GEMM (f32 out), grid 16x32 ----------
__global__ __launch_bounds__(256) void gemm_nt_f32(const unsigned short* __restrict__ A,
                                                   const unsigned short* __restrict__ Bw,
                                                   float* __restrict__ C,
                                                   int M, int N, int K) {
  __shared__ unsigned short As[128 * 64];
  __shared__ unsigned short Bs[128 * 64];
  const int tid = threadIdx.x;
  const int lane = tid & 63, w = tid >> 6;
  const int quad = lane >> 4, l15 = lane & 15;
  const int wm = w >> 1, wn = w & 1;
  // XCD-aware swizzle: grid 16x32, each XCD owns cols [2k, 2k+2)
  const int lin = blockIdx.y * 16 + blockIdx.x;
  const int sub = lin >> 3;
  const int m0 = (sub >> 1) * 128;
  const int n0 = ((lin & 7) * 2 + (sub & 1)) * 128;

  floatx4 acc[4][4];
#pragma unroll
  for (int i = 0; i < 4; ++i)
#pragma unroll
    for (int j = 0; j < 4; ++j) acc[i][j] = (floatx4){0.f, 0.f, 0.f, 0.f};

  const int ar = tid >> 3;
  const int ac = (((tid & 7) ^ (ar & 7)) * 8);
  const unsigned short* Abase = A + (size_t)(m0 + ar) * K + ac;
  const unsigned short* Bbase = Bw + (size_t)(n0 + ar) * K + ac;

  for (int k0 = 0; k0 < K; k0 += 64) {
    __syncthreads();
#pragma unroll
    for (int p = 0; p < 4; ++p) {
      load_lds16(Abase + (size_t)(p * 32) * K + k0, (char*)As + p * 4096 + tid * 16);
      load_lds16(Bbase + (size_t)(p * 32) * K + k0, (char*)Bs + p * 4096 + tid * 16);
    }
    __syncthreads();
#pragma unroll
    for (int ks = 0; ks < 2; ++ks) {
      short8 af[4], bfr[4];
      const int key = (((ks << 2) + quad) ^ (l15 & 7)) << 4;
#pragma unroll
      for (int i = 0; i < 4; ++i)
        af[i] = *(const short8*)((const char*)As + (wm * 64 + i * 16 + l15) * 128 + key);
#pragma unroll
      for (int j = 0; j < 4; ++j)
        bfr[j] = *(const short8*)((const char*)Bs + (wn * 64 + j * 16 + l15) * 128 + key);
#pragma unroll
      for (int i = 0; i < 4; ++i)
#pragma unroll
        for (int j = 0; j < 4; ++j)
          acc[i][j] = __builtin_amdgcn_mfma_f32_16x16x32_bf16(af[i], bfr[j], acc[i][j], 0, 0, 0);
    }
  }
#pragma unroll
  for (int i = 0; i < 4; ++i) {
    const int row = m0 + wm * 64 + i * 16 + quad * 4;
#pragma unroll
    for (int j = 0; j < 4; ++j) {
      const int col = n0 + wn * 64 + j * 16 + l15;
#pragma unroll
      for (int r = 0; r < 4; ++r)
        C[(size_t)(row + r) * N + col] = acc[i][j][r];
    }
  }
}

// ---------- 2: causal flash attention v7 ----------
// grid (32, 2, 16) = (head, batch, qz); qt = 15 - qz, z slowest-varying so
// the heavy diagonal tiles (qt=15, 32 kv-steps) dispatch FIRST -> greedy
// LPT balance across 1024 blocks. 3 blocks resident/CU (LDS 51200*3=150KB)
// = 12 waves/CU vs v6's 8 (v6's 512-block grid capped occupancy at 2/CU).
// kv-loop unrolled by 2 (trip count 2qt+2 always even): compile-time buffer
// indices, pointer-increment prefetch, mask only in last 2 tiles.
// T5 setprio(1) wraps the MFMA clusters (independent blocks per CU ->
// scheduler has role diversity, the regime where setprio measured +4-7%).
// LDS: K[2] 2x8192 | V[2] 2x8192 | P 4x4608  = 51200 B
__global__ __launch_bounds__(256) void attn_kernel(const unsigned short* __restrict__ qk,
                                                   const unsigned short* __restrict__ vT,
                                                   unsigned short* __restrict__ attn) {
  const int h = blockIdx.x, b = blockIdx.y;
  const int qt = 15 - (int)blockIdx.z;  // heavy-first dispatch
  const int hk = h >> 2;
  const int tid = threadIdx.x;
  const int w = tid >> 6, lane = tid & 63, quad = lane >> 4, l15 = lane & 15;

  __shared__ char lds[51200];
  unsigned short* Pq = (unsigned short*)(lds + 32768 + w * 4608);  // [32 q][72 kk]

  const int srow = tid >> 3;                    // staging row
  const int sgrp = ((tid & 7) ^ (srow & 7));    // swizzled source col-group
  const int relbase = w * 32 + l15;             // for causal mask (q local)

  const short8 ones = {16256, 16256, 16256, 16256, 16256, 16256, 16256, 16256};  // bf16 1.0

  const size_t rowQ = (size_t)(b * TT + qt * 128);

  // ---- stage Q tile (128x64, swizzled) into K/V region ----
  {
    const unsigned short* qsrc = qk + (rowQ + srow) * QKN + h * 64 + sgrp * 8;
#pragma unroll
    for (int p = 0; p < 4; ++p)
      load_lds16(qsrc + (size_t)p * 32 * QKN, lds + p * 4096 + tid * 16);
  }
  __syncthreads();
  short8 qf[2][2];  // B-operand frags: Q[q=l15(+i*16)][d=ks*32+quad*8..]
#pragma unroll
  for (int i = 0; i < 2; ++i)
#pragma unroll
    for (int ks = 0; ks < 2; ++ks)
      qf[i][ks] = *(const short8*)(lds + (w * 32 + i * 16 + l15) * 128 +
                                   ((((ks << 2) + quad) ^ (l15 & 7)) << 4));
  __syncthreads();  // all waves done reading Q before K(0)/V(0) overwrite

  floatx4 accO[2][4], accL[2];
#pragma unroll
  for (int i = 0; i < 2; ++i) {
    accL[i] = (floatx4){0.f, 0.f, 0.f, 0.f};
#pragma unroll
    for (int j = 0; j < 4; ++j) accO[i][j] = (floatx4){0.f, 0.f, 0.f, 0.f};
  }

  // ---- prefetch pointers (advance by one 64-row tile per step) ----
  const unsigned short* kptr =
      qk + (size_t)(b * TT + srow) * QKN + KOFF + hk * 64 + sgrp * 8;
  const unsigned short* vptr =
      vT + (size_t)(hk * 64 + srow) * 4096 + b * TT + sgrp * 8;

  // ---- prologue: stage tile 0 into buf0 ----
  load_lds16(kptr, lds + tid * 16);
  load_lds16(kptr + (size_t)32 * QKN, lds + 4096 + tid * 16);
  load_lds16(vptr, lds + 16384 + tid * 16);
  load_lds16(vptr + (size_t)32 * 4096, lds + 16384 + 4096 + tid * 16);
  kptr += (size_t)64 * QKN;
  vptr += 64;
  __syncthreads();

  // one kv-tile step; BUF/PREF/MREL become compile-time after inlining
  auto step = [&](const int BUF, const bool PREF, const int MREL) {
    if (PREF) {
      char* kd = lds + ((BUF ^ 1) * 8192);
      char* vd = lds + 16384 + ((BUF ^ 1) * 8192);
      load_lds16(kptr, kd + tid * 16);
      load_lds16(kptr + (size_t)32 * QKN, kd + 4096 + tid * 16);
      load_lds16(vptr, vd + tid * 16);
      load_lds16(vptr + (size_t)32 * 4096, vd + 4096 + tid * 16);
      kptr += (size_t)64 * QKN;
      vptr += 64;
    }

    // ---- S^T = K Q^T : D[kk_local][q_local] (scale pre-folded into Q) ----
    const char* Ks = lds + BUF * 8192;
    floatx4 st[2][4];  // [i=q-tile][jm=kk-tile]
    __builtin_amdgcn_s_setprio(1);
#pragma unroll
    for (int jm = 0; jm < 4; ++jm) {
      const int krow = jm * 16 + l15;
      const short8 kf0 = *(const short8*)(Ks + krow * 128 + ((quad ^ (l15 & 7)) << 4));
      const short8 kf1 = *(const short8*)(Ks + krow * 128 + (((4 + quad) ^ (l15 & 7)) << 4));
#pragma unroll
      for (int i = 0; i < 2; ++i) {
        floatx4 z = (floatx4){0.f, 0.f, 0.f, 0.f};
        z = __builtin_amdgcn_mfma_f32_16x16x32_bf16(kf0, qf[i][0], z, 0, 0, 0);
        st[i][jm] = __builtin_amdgcn_mfma_f32_16x16x32_bf16(kf1, qf[i][1], z, 0, 0, 0);
      }
    }
    __builtin_amdgcn_s_setprio(0);

    // ---- hoist V-fragment LDS reads: latency overlaps softmax VALU ----
    const char* Vt = lds + 16384 + BUF * 8192;
    short8 vf[2][4];
#pragma unroll
    for (int ks = 0; ks < 2; ++ks)
#pragma unroll
      for (int jd = 0; jd < 4; ++jd) {
        const int d = jd * 16 + l15;
        vf[ks][jd] = *(const short8*)(Vt + d * 128 +
                                      ((((ks << 2) + quad) ^ (l15 & 7)) << 4));
      }

    // ---- fixed-max softmax: P = exp2(st); mask only when MREL >= 0 ----
#pragma unroll
    for (int i = 0; i < 2; ++i) {
#pragma unroll
      for (int jm = 0; jm < 4; ++jm) {
        float e0 = exp2f(st[i][jm][0]);
        float e1 = exp2f(st[i][jm][1]);
        float e2 = exp2f(st[i][jm][2]);
        float e3 = exp2f(st[i][jm][3]);
        if (MREL >= 0) {
          const int rel = relbase + i * 16 - MREL;  // lane's local q
          const int kg = jm * 16 + quad * 4;
          if (kg > rel) e0 = 0.f;
          if (kg + 1 > rel) e1 = 0.f;
          if (kg + 2 > rel) e2 = 0.f;
          if (kg + 3 > rel) e3 = 0.f;
        }
        ushort4 pk;
        pk.x = f2bf(e0); pk.y = f2bf(e1); pk.z = f2bf(e2); pk.w = f2bf(e3);
        *(ushort4*)(Pq + (i * 16 + l15) * 72 + jm * 16 + quad * 4) = pk;
      }
    }
    asm volatile("s_waitcnt lgkmcnt(0)" ::: "memory");  // wave-local P w->r

    // ---- O += P V ; l += P . 1 ----
    __builtin_amdgcn_s_setprio(1);
#pragma unroll
    for (int ks = 0; ks < 2; ++ks) {
      short8 pf[2];
#pragma unroll
      for (int i2 = 0; i2 < 2; ++i2)
        pf[i2] = *(const short8*)(Pq + (i2 * 16 + l15) * 72 + ks * 32 + quad * 8);
      accL[0] = __builtin_amdgcn_mfma_f32_16x16x32_bf16(pf[0], ones, accL[0], 0, 0, 0);
      accL[1] = __builtin_amdgcn_mfma_f32_16x16x32_bf16(pf[1], ones, accL[1], 0, 0, 0);
#pragma unroll
      for (int jd = 0; jd < 4; ++jd) {
        accO[0][jd] = __builtin_amdgcn_mfma_f32_16x16x32_bf16(pf[0], vf[ks][jd], accO[0][jd], 0, 0, 0);
        accO[1][jd] = __builtin_amdgcn_mfma_f32_16x16x32_bf16(pf[1], vf[ks][jd], accO[1][jd], 0, 0, 0);
      }
    }
    __builtin_amdgcn_s_setprio(0);
    __syncthreads();  // drains prefetch + protects buffer overwrite
  };

  // steady: 2*qt unmasked tiles (pairs), then 2 masked diagonal tiles
  for (int t2 = 0; t2 < qt; ++t2) {
    step(0, true, -1);
    step(1, true, -1);
  }
  step(0, true, 0);
  step(1, false, 64);

  // ---- epilogue: O / l -> attn  (accL C-layout rows match accO rows) ----
#pragma unroll
  for (int i2 = 0; i2 < 2; ++i2) {
#pragma unroll
    for (int jd = 0; jd < 4; ++jd) {
      const int col = h * 64 + jd * 16 + l15;
#pragma unroll
      for (int r = 0; r < 4; ++r) {
        const size_t row = rowQ + w * 32 + i2 * 16 + quad * 4 + r;
        attn[row * TC + col] = f2bf(accO[i2][jd][r] / accL[i2][r]);
      }
    }
  }
}

// ---------- launch ----------
extern "C" void kernel_launch(void* const* d_in, const int* in_sizes, int n_in,
                              void* d_out, int out_size, void* d_ws, size_t ws_size,
                              hipStream_t stream) {
  const float* x = (const float*)d_in[0];
  const float* Wq = (const float*)d_in[1];
  const float* Wk = (const float*)d_in[2];
  const float* Wv = (const float*)d_in[3];
  const float* Wo = (const float*)d_in[4];
  float* out = (float*)d_out;

  char* ws = (char*)d_ws;
  unsigned short* xb   = (unsigned short*)(ws);               // 4096x2048 bf16
  unsigned short* wqkv = (unsigned short*)(ws + 16777216);    // 3072x2048 bf16
  unsigned short* wob  = (unsigned short*)(ws + 29360128);    // 2048x2048 bf16
  unsigned short* qk   = (unsigned short*)(ws + 37748736);    // 4096x2560 bf16 (Q|K, roped)
  unsigned short* vT   = (unsigned short*)(ws + 58720256);    // 512x4096 bf16 (V transposed)
  unsigned short* attn = (unsigned short*)(ws + 62914560);    // 4096x2048 bf16
  // rope table (512 KB) overlays the attn buffer: written by cast_all, read by
  // gemm_qkv, then overwritten by attn_kernel (all stream-ordered).
  float2* ropeTab = (float2*)(ws + 62914560);
  // total ws use: 79,691,776 bytes

  cast_all<<<18432, 256, 0, stream>>>(x, Wq, Wk, Wv, Wo, xb, wqkv, wob, ropeTab);
  gemm_qkv<<<dim3(24, 32), 256, 0, stream>>>(xb, wqkv, qk, vT, ropeTab);
  attn_kernel<<<dim3(32, 2, 16), 256, 0, stream>>>(qk, vT, attn);
  gemm_nt_f32<<<dim3(16, 32), 256, 0, stream>>>(attn, wob, out, 4096, TC, 2048);
}